// Round 8
// baseline (364.275 us; speedup 1.0000x reference)
//
#include <hip/hip_runtime.h>
#include <cstdint>
#include <math.h>

#define NCLS  20
#define MSZ   512
#define DIM   256
#define HW    16384      // 128*128
#define NPIX  131072     // 4 * 2 * 16384
#define AROWS 10240      // NCLS * MSZ
#define TEMP_INV 10.0f
#define EXP2K 14.4269504088896f   // TEMP_INV * log2(e)

typedef __attribute__((ext_vector_type(8))) short bf16x8;
typedef __attribute__((ext_vector_type(4))) float f32x4;

__device__ __forceinline__ short f2bf(float f) {
    unsigned u = __float_as_uint(f);
    unsigned r = (u + 0x7FFFu + ((u >> 16) & 1u)) >> 16;
    return (short)r;
}
__device__ __forceinline__ float bf2f(short s) {
    return __uint_as_float(((unsigned)(unsigned short)s) << 16);
}
__device__ __forceinline__ float fexp2(float x) {
    float r;
    asm volatile("v_exp_f32 %0, %1" : "=v"(r) : "v"(x));
    return r;
}
// async global->LDS, 16B/lane, wave-uniform LDS base + lane*16 (global source per-lane)
__device__ __forceinline__ void gld16(const void* g, void* l) {
    __builtin_amdgcn_global_load_lds(
        (const __attribute__((address_space(1))) unsigned int*)(uintptr_t)g,
        (__attribute__((address_space(3))) unsigned int*)(unsigned int)(uintptr_t)l,
        16, 0, 0);
}

// zero-region float layout (15488 floats = 61952 B), zeroed by k_histwrite phase 1:
//   [0]       row_sumexp   (10240)
//   [10240]   S            (5120)
//   [15360]   pcnt         (20 ints)
//   [15380]   facc[2]      (loss sum, valid count)
//   [15382]   done_cnt     (int)
//   [15383]   rb_cnt       (80 ints, per-row-block completion counters)
#define ZREG_FLOATS 15488

// ---------------- K1: fused labels + histogram + ordered compaction (resident-grid sync) ----------------
// 512 blocks x 256 threads: always fully co-resident (capacity 2048 blocks at this size), so a
// device-scope flag spin between phase 1 (per-chunk histogram) and phase 2 (prefix + compaction)
// is deadlock-free. Labels live in registers (no global labels buffer, one launch fewer).
// Release: __threadfence (L2 writeback) before flag inc. Acquire: __threadfence (L2 inv) after spin.
__global__ __launch_bounds__(256) void k_histwrite(const int* __restrict__ mg,
                                                   const int* __restrict__ ag,
                                                   int* __restrict__ hist,
                                                   int* __restrict__ row2pix,
                                                   int* __restrict__ counts,
                                                   float* __restrict__ zreg,
                                                   int* __restrict__ hflag) {
    int chunk = blockIdx.x, t = threadIdx.x;
    int lane = t & 63, wv = t >> 6;
    int gi = chunk * 256 + t;
    if (gi < ZREG_FLOATS) zreg[gi] = 0.0f;
    if (gi < AROWS) row2pix[gi] = -1;   // lines block-exclusive (256 ints/block)

    int n = gi;
    int b = n >> 15, r = n & 32767;
    const int* g = (r < HW) ? mg : ag;
    int p = (r < HW) ? r : (r - HW);
    int h = p >> 7, w = p & 127;
    int lab = g[(((size_t)b * 512) + (size_t)(h << 2)) * 512 + (size_t)(w << 2)];
    if (lab == 255) lab = -1;
    else if (lab == 254) lab = NCLS - 1;

    __shared__ int cnt20[NCLS];
    __shared__ int cbase[NCLS];
    __shared__ int wcnt2[4][NCLS];
    if (t < NCLS) cnt20[t] = 0;
    __syncthreads();
    int myrank = 0;
#pragma unroll
    for (int c = 0; c < NCLS; ++c) {
        unsigned long long m = __ballot(lab == c);
        if (lane == 0) {
            wcnt2[wv][c] = __popcll(m);
            if (m) atomicAdd(&cnt20[c], __popcll(m));
        }
        if (lab == c) myrank = __popcll(m & ((1ull << lane) - 1ull));
    }
    __syncthreads();
    if (t < NCLS) hist[t * 512 + chunk] = cnt20[t];
    __syncthreads();                       // drains this block's stores (vmcnt) pre-fence
    if (t == 0) {
        __threadfence();                   // release: writeback hist + row2pix inits
        atomicAdd(hflag, 1);
        while (atomicAdd(hflag, 0) < 512) __builtin_amdgcn_s_sleep(8);
    }
    __syncthreads();
    __threadfence();                       // acquire: invalidate stale cached hist lines

    // phase 2: prefix over chunks < chunk, then ordered compaction write
#pragma unroll
    for (int cc5 = 0; cc5 < 5; ++cc5) {
        int c = wv * 5 + cc5;
        int s = 0;
        for (int j = lane; j < chunk; j += 64) s += hist[c * 512 + j];
#pragma unroll
        for (int o = 32; o > 0; o >>= 1) s += __shfl_down(s, o, 64);
        if (lane == 0) cbase[c] = s;
    }
    __syncthreads();
    if (lab >= 0) {
        int base = cbase[lab] + myrank;
        for (int w2 = 0; w2 < wv; ++w2) base += wcnt2[w2][lab];
        if (base < MSZ) row2pix[lab * MSZ + base] = n;
    }
    if (chunk == 511 && t < NCLS)
        counts[t] = cbase[t] + wcnt2[0][t] + wcnt2[1][t] + wcnt2[2][t] + wcnt2[3][t];
}

// ---------------- K2: fused gather + normalize + bank update + per-class S/pcnt ----------------
// Each row gathers its 256 channels directly from proj via row2pix (selected pixels are a dense
// scan-order prefix -> gathers are line-dense, ~11 MB unique). 640 blocks, 16 rows each.
__global__ __launch_bounds__(256) void k_nbc(const float* __restrict__ mainp,
                                             const float* __restrict__ auxp,
                                             const int* __restrict__ row2pix,
                                             const float* __restrict__ bank,
                                             const int* __restrict__ counts,
                                             short* __restrict__ anchorsB,
                                             short* __restrict__ contrasB,
                                             int* __restrict__ c_valid,
                                             float* __restrict__ S,
                                             int* __restrict__ pcnt) {
    int blk = blockIdx.x;
    int c = blk >> 5;                  // 32 blocks per class
    int t = threadIdx.x, lane = t & 63, wv = t >> 6;
    int cc = counts[c];
    int base = blk * 16;
    float sacc[4] = {0.f, 0.f, 0.f, 0.f};
    int vcnt = 0;

#pragma unroll
    for (int it = 0; it < 4; ++it) {
        int a = base + it * 4 + wv;
        int m = a & 511;
        int n = row2pix[a];            // wave-uniform broadcast load
        float x[4];
        if (n >= 0) {
            int b = n >> 15, r = n & 32767;
            const float* src = (r < HW) ? mainp : auxp;
            int p = (r < HW) ? r : (r - HW);
            const float* gp = src + (size_t)b * DIM * HW + p;
#pragma unroll
            for (int q = 0; q < 4; ++q)
                x[q] = gp[(size_t)(lane * 4 + q) * HW];
        } else {
            x[0] = x[1] = x[2] = x[3] = 0.0f;   // unreachable when counts >= MSZ; masked downstream
        }
        float ss = x[0]*x[0] + x[1]*x[1] + x[2]*x[2] + x[3]*x[3];
#pragma unroll
        for (int o = 1; o < 64; o <<= 1) ss += __shfl_xor(ss, o, 64);
        float scale = 1.0f / fmaxf(sqrtf(ss), 1e-12f);
        float ax[4];
#pragma unroll
        for (int q = 0; q < 4; ++q) ax[q] = x[q] * scale;
        short4 oa;
        oa.x = f2bf(ax[0]); oa.y = f2bf(ax[1]); oa.z = f2bf(ax[2]); oa.w = f2bf(ax[3]);
        *(short4*)&anchorsB[(size_t)a * DIM + lane * 4] = oa;

        bool upd = m < cc;
        float4 bv = *(const float4*)&bank[(size_t)a * DIM + lane * 4];
        float u[4];
        u[0] = upd ? 0.999f * bv.x + 0.001f * ax[0] : bv.x;
        u[1] = upd ? 0.999f * bv.y + 0.001f * ax[1] : bv.y;
        u[2] = upd ? 0.999f * bv.z + 0.001f * ax[2] : bv.z;
        u[3] = upd ? 0.999f * bv.w + 0.001f * ax[3] : bv.w;
        float ss2 = u[0]*u[0] + u[1]*u[1] + u[2]*u[2] + u[3]*u[3];
#pragma unroll
        for (int o = 1; o < 64; o <<= 1) ss2 += __shfl_xor(ss2, o, 64);
        float nrm = sqrtf(ss2);
        float inv = 1.0f / fmaxf(nrm, 1e-12f);
        short oc[4];
        oc[0] = f2bf(upd ? u[0] * inv : bv.x);
        oc[1] = f2bf(upd ? u[1] * inv : bv.y);
        oc[2] = f2bf(upd ? u[2] * inv : bv.z);
        oc[3] = f2bf(upd ? u[3] * inv : bv.w);
        *(short4*)&contrasB[(size_t)a * DIM + lane * 4] = *(short4*)oc;
        bool valid = nrm > 0.0f;
        if (lane == 0) {
            c_valid[a] = valid ? 1 : 0;
            vcnt += valid ? 1 : 0;
        }
        if (valid) {
#pragma unroll
            for (int q = 0; q < 4; ++q) sacc[q] += bf2f(oc[q]);
        }
    }

    __shared__ float s4[4][DIM];
    __shared__ int pv[4];
#pragma unroll
    for (int q = 0; q < 4; ++q) s4[wv][lane * 4 + q] = sacc[q];
    if (lane == 0) pv[wv] = vcnt;
    __syncthreads();
    float s = s4[0][t] + s4[1][t] + s4[2][t] + s4[3][t];
    atomicAdd(&S[c * DIM + t], s);
    if (t == 0) atomicAdd(&pcnt[c], pv[0] + pv[1] + pv[2] + pv[3]);
}

// ---------------- K3: bf16 MFMA scores + fused sum-exp + FUSED per-row loss tail ----------------
// GEMM core FROZEN (r3/r6/r7 config: 128x256 tile, 8 waves 64x64, BK=64 single-buffer 48 KiB,
// full XOR swizzle = measured-0 conflicts, 2 blocks/CU, 76-79 us, 28.8% MfmaUtil = 705 TF at
// the 2-phase structural ceiling; K=256 gives no steady state for deeper pipelines).
// NEW: k_fin folded into the epilogue. Each row-block (blockIdx.x, 80 of them) has 40
// col-blocks; the 40th to finish (rb_cnt) computes the 128-row loss tail (anchor.S dot + lse)
// while other blocks still run GEMM -> the old k_fin launch + execution hides entirely.
__global__ __launch_bounds__(512, 4) void k_score(const short* __restrict__ A,
                                                  const short* __restrict__ Bc,
                                                  const int* __restrict__ c_valid,
                                                  float* __restrict__ row_sumexp,
                                                  const float* __restrict__ S,
                                                  const int* __restrict__ counts,
                                                  const int* __restrict__ pcnt,
                                                  float* __restrict__ facc,
                                                  int* __restrict__ done_cnt,
                                                  int* __restrict__ rb_cnt,
                                                  float* __restrict__ out) {
    __shared__ short As[128 * 64];   // 16 KiB
    __shared__ short Bs[256 * 64];   // 32 KiB
    const int t = threadIdx.x;
    const int lane = t & 63, wv = t >> 6;
    const int wr = wv & 1, wc = wv >> 1;    // wave tile: rows wr*64..+64, cols wc*64..+64
    const int qr = lane >> 4, qc = lane & 15;
    const int s7 = qc & 7;
    const int row0 = blockIdx.x * 128, col0 = blockIdx.y * 256;

    // staging: thread t covers row rl8 = t>>3 of each 64-row chunk, linear slot t&7.
    // source fetches data slot sdat = (t&7)^(row&7) so LDS(row, slot) holds data slot^(row&7).
    const int rl8 = t >> 3;
    const int sdat = (t & 7) ^ (rl8 & 7);
    const short* Ag = A  + (size_t)row0 * DIM;
    const short* Bg = Bc + (size_t)col0 * DIM;

    // frag-read slot offsets (shorts): data slot kk*4+qr lives at ((kk*4+qr)^(row&7)),
    // row&7 == qc&7 for all fragment rows (row = mult8 + qc).
    const int sl0 = ((0 + qr) ^ s7) * 8;
    const int sl1 = ((4 + qr) ^ s7) * 8;

    f32x4 acc[4][4] = {};                   // [rt][ct]

    auto stage = [&](int kt) {
#pragma unroll
        for (int r = 0; r < 2; ++r)
            gld16(Ag + (size_t)(r * 64 + rl8) * DIM + kt * 64 + sdat * 8,
                  &As[(r * 64 + wv * 8) * 64]);
#pragma unroll
        for (int r = 0; r < 4; ++r)
            gld16(Bg + (size_t)(r * 64 + rl8) * DIM + kt * 64 + sdat * 8,
                  &Bs[(r * 64 + wv * 8) * 64]);
    };

    stage(0);
    for (int kt = 0; kt < 4; ++kt) {
        asm volatile("s_waitcnt vmcnt(0)" ::: "memory");   // stage(kt) landed (issued 1 tile ago)
        asm volatile("s_barrier" ::: "memory");            // buffer ready for all waves

        bf16x8 a0[4], b0[4], a1[4], b1[4];
#pragma unroll
        for (int rt = 0; rt < 4; ++rt)
            a0[rt] = *(const bf16x8*)&As[(wr * 64 + rt * 16 + qc) * 64 + sl0];
#pragma unroll
        for (int ct = 0; ct < 4; ++ct)
            b0[ct] = *(const bf16x8*)&Bs[(wc * 64 + ct * 16 + qc) * 64 + sl0];
#pragma unroll
        for (int rt = 0; rt < 4; ++rt)
#pragma unroll
            for (int ct = 0; ct < 4; ++ct)
                acc[rt][ct] = __builtin_amdgcn_mfma_f32_16x16x32_bf16(a0[rt], b0[ct], acc[rt][ct], 0, 0, 0);
#pragma unroll
        for (int rt = 0; rt < 4; ++rt)
            a1[rt] = *(const bf16x8*)&As[(wr * 64 + rt * 16 + qc) * 64 + sl1];
#pragma unroll
        for (int ct = 0; ct < 4; ++ct)
            b1[ct] = *(const bf16x8*)&Bs[(wc * 64 + ct * 16 + qc) * 64 + sl1];

        asm volatile("s_waitcnt lgkmcnt(0)" ::: "memory"); // all my ds_reads complete
        __builtin_amdgcn_sched_barrier(0);                 // (rule 18) nothing hoists above
        asm volatile("s_barrier" ::: "memory");            // all waves done reading buffer
        if (kt < 3) stage(kt + 1);                         // async overwrite, lands during MFMA+next wait

#pragma unroll
        for (int rt = 0; rt < 4; ++rt)
#pragma unroll
            for (int ct = 0; ct < 4; ++ct)
                acc[rt][ct] = __builtin_amdgcn_mfma_f32_16x16x32_bf16(a1[rt], b1[ct], acc[rt][ct], 0, 0, 0);
    }

    // fused masked sum-exp epilogue: per row-partial over this block's 256 cols
    float cm[4];
#pragma unroll
    for (int ct = 0; ct < 4; ++ct)
        cm[ct] = c_valid[col0 + wc * 64 + ct * 16 + qc] ? 1.0f : 0.0f;
#pragma unroll
    for (int rt = 0; rt < 4; ++rt)
#pragma unroll
        for (int r = 0; r < 4; ++r) {
            float e = cm[0] * fexp2(acc[rt][0][r] * EXP2K)
                    + cm[1] * fexp2(acc[rt][1][r] * EXP2K)
                    + cm[2] * fexp2(acc[rt][2][r] * EXP2K)
                    + cm[3] * fexp2(acc[rt][3][r] * EXP2K);
#pragma unroll
            for (int o = 1; o < 16; o <<= 1) e += __shfl_xor(e, o, 64);
            if (qc == 0)
                atomicAdd(&row_sumexp[row0 + wr * 64 + rt * 16 + qr * 4 + r], e);
        }

    // ---- fused loss tail: 40th finisher of this row-block computes its 128 rows ----
    __shared__ int fin_s;
    __syncthreads();                       // drains all waves' row_sumexp atomics (vmcnt) first
    if (t == 0) {
        __threadfence();
        unsigned cdone = atomicAdd((unsigned*)&rb_cnt[blockIdx.x], 1u);
        fin_s = (cdone == 39u) ? 1 : 0;
    }
    __syncthreads();
    if (!fin_s) return;
    __threadfence();                       // acquire

    const int c = row0 >> 9;               // 128-row block lies within one class (128 | 512)
    const int pc = pcnt[c], cc = counts[c];
    float lsum = 0.0f, vcn = 0.0f;
    for (int it = 0; it < 16; ++it) {
        int a = row0 + wv * 16 + it;       // 8 waves x 16 rows = 128
        short4 a4 = *(const short4*)&A[(size_t)a * DIM + lane * 4];
        float4 sv = *(const float4*)&S[c * DIM + lane * 4];
        float dot = bf2f(a4.x) * sv.x + bf2f(a4.y) * sv.y
                  + bf2f(a4.z) * sv.z + bf2f(a4.w) * sv.w;
#pragma unroll
        for (int o = 1; o < 64; o <<= 1) dot += __shfl_xor(dot, o, 64);
        if (lane == 0 && (a & 511) < cc && pc > 0) {
            float lse = logf(atomicAdd(&row_sumexp[a], 0.0f));   // coherent read-back
            lsum += (TEMP_INV * dot - (float)pc * lse) / (float)pc;
            vcn += 1.0f;
        }
    }
    __shared__ float wls[8], wvc[8];
    if (lane == 0) { wls[wv] = lsum; wvc[wv] = vcn; }
    __syncthreads();
    if (t == 0) {
        float L8 = 0.f, V8 = 0.f;
#pragma unroll
        for (int i2 = 0; i2 < 8; ++i2) { L8 += wls[i2]; V8 += wvc[i2]; }
        atomicAdd(&facc[0], L8);
        atomicAdd(&facc[1], V8);
        __threadfence();
        unsigned d = atomicAdd((unsigned*)done_cnt, 1u);
        if (d == 79u) {                    // last row-block: totals visible via atomics
            __threadfence();
            float L = atomicAdd(&facc[0], 0.0f);
            float V = atomicAdd(&facc[1], 0.0f);
            out[0] = -L / fmaxf(V, 1.0f);
        }
    }
}

// ---------------- launch ----------------
extern "C" void kernel_launch(void* const* d_in, const int* in_sizes, int n_in,
                              void* d_out, int out_size, void* d_ws, size_t ws_size,
                              hipStream_t stream) {
    const float* main_proj = (const float*)d_in[0];
    const int*   main_gt   = (const int*)d_in[1];
    const float* aux_proj  = (const float*)d_in[2];
    const int*   aux_gt    = (const int*)d_in[3];
    const float* bank      = (const float*)d_in[4];
    float* out = (float*)d_out;

    char* ws = (char*)d_ws;
    int*   hist       = (int*)(ws + 524288);         // 40960 B
    int*   row2pix    = (int*)(ws + 565248);         // 40960 B used
    int*   c_valid    = (int*)(ws + 1089536);        // 40960 B
    float* zreg       = (float*)(ws + 1130496);      // 61952 B zero region (zeroed by k_histwrite)
    float* row_sumexp = zreg;
    float* S          = zreg + 10240;
    int*   pcnt       = (int*)(zreg + 15360);
    float* facc       = zreg + 15380;
    int*   done_cnt   = (int*)(zreg + 15382);
    int*   rb_cnt     = (int*)(zreg + 15383);        // 80 ints
    int*   counts     = (int*)(ws + 1192448);        // 256 B (written by k_histwrite)
    int*   hflag      = (int*)(ws + 1192704);        // 4 B, must be pre-zeroed (used DURING zeroing kernel)
    short* anchorsB   = (short*)(ws + 11678464);     // 5242880 B
    short* contrasB   = (short*)(ws + 16921344);     // 5242880 B (end 22164224)

    hipMemsetAsync(hflag, 0, 4, stream);
    k_histwrite<<<512, 256, 0, stream>>>(main_gt, aux_gt, hist, row2pix, counts, zreg, hflag);
    k_nbc<<<AROWS / 16, 256, 0, stream>>>(main_proj, aux_proj, row2pix, bank, counts,
                                          anchorsB, contrasB, c_valid, S, pcnt);
    dim3 grid(AROWS / 128, AROWS / 256);
    k_score<<<grid, 512, 0, stream>>>(anchorsB, contrasB, c_valid, row_sumexp,
                                      S, counts, pcnt, facc, done_cnt, rb_cnt, out);
}